// Round 4
// baseline (470.797 us; speedup 1.0000x reference)
//
#include <hip/hip_runtime.h>

// Problem constants (from reference)
#define NVN 65536
#define NCN 32768
#define NB 4
#define DIM 32
#define NE 262144
#define HID 40
#define MSGD 20

#define WE2_STRIDE 36  // padded row stride for we2s (breaks h-row bank aliasing)

__device__ __forceinline__ void fma4(float4& acc, float a, const float4 w) {
    acc.x += a * w.x; acc.y += a * w.y; acc.z += a * w.z; acc.w += a * w.w;
}
__device__ __forceinline__ void relu_acc4(float4& s, const float4 u, const float4 t) {
    s.x += fmaxf(u.x + t.x, 0.f); s.y += fmaxf(u.y + t.y, 0.f);
    s.z += fmaxf(u.z + t.z, 0.f); s.w += fmaxf(u.w + t.w, 0.f);
}

// ---------------- CSR build (both sides fused) ----------------

__global__ __launch_bounds__(256) void hist_both(const int* __restrict__ to_x,
                                                 const int* __restrict__ to_z,
                                                 int* __restrict__ cnt_x,
                                                 int* __restrict__ cnt_z) {
    int bid = blockIdx.x;
    int e = (bid & 1023) * 256 + threadIdx.x;
    if (bid < 1024) atomicAdd(&cnt_x[to_x[e]], 1);
    else            atomicAdd(&cnt_z[to_z[e]], 1);
}

__global__ __launch_bounds__(1024) void scan_both(int* __restrict__ cnt_x,
                                                  int* __restrict__ cnt_z,
                                                  int* __restrict__ start_x,
                                                  int* __restrict__ start_z) {
    int side = blockIdx.x;
    int* counts = side ? cnt_z : cnt_x;   // re-written in place as scatter cursor
    int* start  = side ? start_z : start_x;
    __shared__ int sd[1024];
    int t = threadIdx.x;
    int base = t * 32;
    int local[32];
    int s = 0;
#pragma unroll
    for (int i = 0; i < 32; i++) { local[i] = counts[base + i]; s += local[i]; }
    sd[t] = s;
    __syncthreads();
    for (int off = 1; off < 1024; off <<= 1) {
        int v = (t >= off) ? sd[t - off] : 0;
        __syncthreads();
        sd[t] += v;
        __syncthreads();
    }
    int run = sd[t] - s;
#pragma unroll
    for (int i = 0; i < 32; i++) {
        start[base + i] = run;
        counts[base + i] = run;   // cursor init
        run += local[i];
    }
    if (t == 1023) start[NCN] = run;
}

__global__ __launch_bounds__(256) void scatter_both(const int* __restrict__ to_x,
                                                    const int* __restrict__ from_x,
                                                    const int* __restrict__ to_z,
                                                    const int* __restrict__ from_z,
                                                    int* __restrict__ cnt_x,
                                                    int* __restrict__ cnt_z,
                                                    unsigned short* __restrict__ ef_x,
                                                    unsigned short* __restrict__ ef_z) {
    int bid = blockIdx.x;
    int e = (bid & 1023) * 256 + threadIdx.x;
    const int* t; const int* f; int* cur; unsigned short* ef;
    if (bid < 1024) { t = to_x; f = from_x; cur = cnt_x; ef = ef_x; }
    else            { t = to_z; f = from_z; cur = cnt_z; ef = ef_z; }
    int c = t[e];
    int pos = atomicAdd(&cur[c], 1);
    ef[pos] = (unsigned short)f[e];
}

// ------- Precompute U2[v][b][40] = h_from[b][v] @ Wm1[0:32] (quad per v, lane=b) -------

__global__ __launch_bounds__(256) void precompU_kernel(const float* __restrict__ h_from,
                                                       const float* __restrict__ Wm1,
                                                       float* __restrict__ U2) {
    __shared__ float w[DIM * HID];
    int tid = threadIdx.x;
    for (int i = tid; i < DIM * HID; i += 256) w[i] = Wm1[i];
    __syncthreads();
    int gt = blockIdx.x * 256 + tid;
    int v = gt >> 2;
    int b = gt & 3;
    const float4* hf4 = (const float4*)(h_from + ((size_t)b * NVN + v) * DIM);
    float acc[HID];
#pragma unroll
    for (int h = 0; h < HID; h++) acc[h] = 0.f;
#pragma unroll
    for (int q = 0; q < DIM / 4; q++) {
        float4 x = hf4[q];
#pragma unroll
        for (int h = 0; h < HID; h++) {
            acc[h] += x.x * w[(4 * q + 0) * HID + h];
            acc[h] += x.y * w[(4 * q + 1) * HID + h];
            acc[h] += x.z * w[(4 * q + 2) * HID + h];
            acc[h] += x.w * w[(4 * q + 3) * HID + h];
        }
    }
    float4* dst = (float4*)(U2 + ((size_t)v * NB + b) * HID);
#pragma unroll
    for (int q = 0; q < HID / 4; q++)
        dst[q] = make_float4(acc[4 * q], acc[4 * q + 1], acc[4 * q + 2], acc[4 * q + 3]);
}

// ------- Precompute T2[c][b][40], P2[c][b][40] (8 lanes per c: which x batch) -------

__global__ __launch_bounds__(256) void precompTP_kernel(const float* __restrict__ h_to,
                                                        const float* __restrict__ logit,
                                                        const float* __restrict__ Wm1,
                                                        const float* __restrict__ We1,
                                                        float* __restrict__ T2,
                                                        float* __restrict__ P2) {
    __shared__ float wm1b[DIM * HID];
    __shared__ float we1b[DIM * HID];
    __shared__ float we1l[HID];
    int tid = threadIdx.x;
    for (int i = tid; i < DIM * HID; i += 256) {
        wm1b[i] = Wm1[DIM * HID + i];   // rows 32..63
        we1b[i] = We1[MSGD * HID + i];  // rows 20..51
    }
    if (tid < HID) we1l[tid] = We1[(MSGD + DIM) * HID + tid];  // row 52
    __syncthreads();
    int gt = blockIdx.x * 256 + tid;
    int c = gt >> 3;
    int l8 = gt & 7;
    int b = l8 & 3;
    int which = l8 >> 2;   // 0: T, 1: P
    const float4* h4 = (const float4*)(h_to + ((size_t)b * NCN + c) * DIM);
    float lg = logit[(size_t)b * NCN + c];
    float lginit = which ? lg : 0.f;
    const float* wsel = which ? we1b : wm1b;
    float acc[HID];
#pragma unroll
    for (int h = 0; h < HID; h++) acc[h] = lginit * we1l[h];
#pragma unroll
    for (int q = 0; q < DIM / 4; q++) {
        float4 x = h4[q];
#pragma unroll
        for (int h = 0; h < HID; h++) {
            acc[h] += x.x * wsel[(4 * q + 0) * HID + h];
            acc[h] += x.y * wsel[(4 * q + 1) * HID + h];
            acc[h] += x.z * wsel[(4 * q + 2) * HID + h];
            acc[h] += x.w * wsel[(4 * q + 3) * HID + h];
        }
    }
    float* dstb = (which ? P2 : T2) + ((size_t)c * NB + b) * HID;
    float4* dst = (float4*)dstb;
#pragma unroll
    for (int q = 0; q < HID / 4; q++)
        dst[q] = make_float4(acc[4 * q], acc[4 * q + 1], acc[4 * q + 2], acc[4 * q + 3]);
}

// ------- Fused aggregate + embed MLP: EIGHT lanes per check node -------
// lane = (batch b, half): each lane owns 20 components; 8-lane group gathers one
// contiguous 640B U2 line per edge. m/o partials pair-reduced via shfl_xor(,4).

__global__ __launch_bounds__(256, 4) void agg_kernel(const float* __restrict__ U2,
                                                     const float* __restrict__ T2,
                                                     const float* __restrict__ P2,
                                                     const int* __restrict__ start,
                                                     const unsigned short* __restrict__ ef,
                                                     const float* __restrict__ Wm2,
                                                     const float* __restrict__ We1,
                                                     const float* __restrict__ We2,
                                                     float* __restrict__ out) {
    __shared__ __attribute__((aligned(16))) float wm2s[HID * MSGD];        // [40][20]
    __shared__ __attribute__((aligned(16))) float we1s[MSGD * HID];        // [20][40]
    __shared__ __attribute__((aligned(16))) float we2s[HID * WE2_STRIDE];  // [40][36]
    int tid = threadIdx.x;
    for (int i = tid; i < HID * MSGD; i += 256) { wm2s[i] = Wm2[i]; we1s[i] = We1[i]; }
    for (int i = tid; i < HID * DIM; i += 256) {
        int h = i >> 5, d = i & 31;
        we2s[h * WE2_STRIDE + d] = We2[i];
    }
    __syncthreads();

    int gt = blockIdx.x * 256 + tid;
    int c = gt >> 3;
    int l8 = gt & 7;
    int b = l8 & 3;
    int half = l8 >> 2;
    int hoff = half * 20;   // this lane's component offset within the 40

    // T slice (20 floats)
    const float4* Tp = (const float4*)(T2 + ((size_t)c * NB + b) * HID + hoff);
    float4 t0 = Tp[0], t1 = Tp[1], t2 = Tp[2], t3 = Tp[3], t4 = Tp[4];

    float4 s0, s1, s2, s3, s4;
    s0 = s1 = s2 = s3 = s4 = make_float4(0.f, 0.f, 0.f, 0.f);

    int e0 = start[c], e1 = start[c + 1];
    const float* Ubase = U2 + b * HID + hoff;
    int vcur = (e0 < e1) ? (int)ef[e0] : 0;
    for (int i = e0; i < e1; ++i) {
        int vnext = (i + 1 < e1) ? (int)ef[i + 1] : 0;
        const float4* Up = (const float4*)(Ubase + (size_t)vcur * (NB * HID));
        float4 u0 = Up[0], u1 = Up[1], u2 = Up[2], u3 = Up[3], u4 = Up[4];
        relu_acc4(s0, u0, t0); relu_acc4(s1, u1, t1); relu_acc4(s2, u2, t2);
        relu_acc4(s3, u3, t3); relu_acc4(s4, u4, t4);
        vcur = vnext;
    }

    // ---- m partial: this lane's 20 h-rows of Wm2 ----
    float4 m4[5];
#pragma unroll
    for (int kq = 0; kq < 5; kq++) m4[kq] = make_float4(0.f, 0.f, 0.f, 0.f);
    const float* wmbase = wm2s + hoff * MSGD;
#define MROW(sv, k) { const float4* w4_ = (const float4*)(wmbase + (k) * MSGD); \
    fma4(m4[0], (sv), w4_[0]); fma4(m4[1], (sv), w4_[1]); fma4(m4[2], (sv), w4_[2]); \
    fma4(m4[3], (sv), w4_[3]); fma4(m4[4], (sv), w4_[4]); }
    MROW(s0.x, 0)  MROW(s0.y, 1)  MROW(s0.z, 2)  MROW(s0.w, 3)
    MROW(s1.x, 4)  MROW(s1.y, 5)  MROW(s1.z, 6)  MROW(s1.w, 7)
    MROW(s2.x, 8)  MROW(s2.y, 9)  MROW(s2.z, 10) MROW(s2.w, 11)
    MROW(s3.x, 12) MROW(s3.y, 13) MROW(s3.z, 14) MROW(s3.w, 15)
    MROW(s4.x, 16) MROW(s4.y, 17) MROW(s4.z, 18) MROW(s4.w, 19)
#undef MROW

    float mm[MSGD];
#pragma unroll
    for (int kq = 0; kq < 5; kq++) {
        mm[4 * kq + 0] = m4[kq].x; mm[4 * kq + 1] = m4[kq].y;
        mm[4 * kq + 2] = m4[kq].z; mm[4 * kq + 3] = m4[kq].w;
    }
    // pair-reduce across the two halves (lane ^ 4) -> full m in every lane
#pragma unroll
    for (int k = 0; k < MSGD; k++) mm[k] += __shfl_xor(mm[k], 4);

    // ---- a = relu(m @ We1[0:20] + P) for this lane's 20 components ----
    const float4* Pp = (const float4*)(P2 + ((size_t)c * NB + b) * HID + hoff);
    float4 a0 = Pp[0], a1 = Pp[1], a2 = Pp[2], a3 = Pp[3], a4 = Pp[4];
#pragma unroll
    for (int k = 0; k < MSGD; k++) {
        float mk = mm[k];
        const float4* w4 = (const float4*)(we1s + k * HID + hoff);
        fma4(a0, mk, w4[0]); fma4(a1, mk, w4[1]); fma4(a2, mk, w4[2]);
        fma4(a3, mk, w4[3]); fma4(a4, mk, w4[4]);
    }
    a0.x = fmaxf(a0.x, 0.f); a0.y = fmaxf(a0.y, 0.f); a0.z = fmaxf(a0.z, 0.f); a0.w = fmaxf(a0.w, 0.f);
    a1.x = fmaxf(a1.x, 0.f); a1.y = fmaxf(a1.y, 0.f); a1.z = fmaxf(a1.z, 0.f); a1.w = fmaxf(a1.w, 0.f);
    a2.x = fmaxf(a2.x, 0.f); a2.y = fmaxf(a2.y, 0.f); a2.z = fmaxf(a2.z, 0.f); a2.w = fmaxf(a2.w, 0.f);
    a3.x = fmaxf(a3.x, 0.f); a3.y = fmaxf(a3.y, 0.f); a3.z = fmaxf(a3.z, 0.f); a3.w = fmaxf(a3.w, 0.f);
    a4.x = fmaxf(a4.x, 0.f); a4.y = fmaxf(a4.y, 0.f); a4.z = fmaxf(a4.z, 0.f); a4.w = fmaxf(a4.w, 0.f);

    // ---- o partial: this lane's 20 h-rows of We2 ----
    float4 o4[8];
#pragma unroll
    for (int dq = 0; dq < 8; dq++) o4[dq] = make_float4(0.f, 0.f, 0.f, 0.f);
    const float* wobase = we2s + hoff * WE2_STRIDE;
#define OROW(av, k) { const float4* w4_ = (const float4*)(wobase + (k) * WE2_STRIDE); \
    fma4(o4[0], (av), w4_[0]); fma4(o4[1], (av), w4_[1]); fma4(o4[2], (av), w4_[2]); \
    fma4(o4[3], (av), w4_[3]); fma4(o4[4], (av), w4_[4]); fma4(o4[5], (av), w4_[5]); \
    fma4(o4[6], (av), w4_[6]); fma4(o4[7], (av), w4_[7]); }
    OROW(a0.x, 0)  OROW(a0.y, 1)  OROW(a0.z, 2)  OROW(a0.w, 3)
    OROW(a1.x, 4)  OROW(a1.y, 5)  OROW(a1.z, 6)  OROW(a1.w, 7)
    OROW(a2.x, 8)  OROW(a2.y, 9)  OROW(a2.z, 10) OROW(a2.w, 11)
    OROW(a3.x, 12) OROW(a3.y, 13) OROW(a3.z, 14) OROW(a3.w, 15)
    OROW(a4.x, 16) OROW(a4.y, 17) OROW(a4.z, 18) OROW(a4.w, 19)
#undef OROW

    float oo[DIM];
#pragma unroll
    for (int dq = 0; dq < 8; dq++) {
        oo[4 * dq + 0] = o4[dq].x; oo[4 * dq + 1] = o4[dq].y;
        oo[4 * dq + 2] = o4[dq].z; oo[4 * dq + 3] = o4[dq].w;
    }
#pragma unroll
    for (int d = 0; d < DIM; d++) oo[d] += __shfl_xor(oo[d], 4);

    float4* Orow = (float4*)(out + ((size_t)b * NCN + c) * DIM);
    if (half == 0) {
        Orow[0] = make_float4(oo[0], oo[1], oo[2], oo[3]);
        Orow[1] = make_float4(oo[4], oo[5], oo[6], oo[7]);
        Orow[2] = make_float4(oo[8], oo[9], oo[10], oo[11]);
        Orow[3] = make_float4(oo[12], oo[13], oo[14], oo[15]);
    } else {
        Orow[4] = make_float4(oo[16], oo[17], oo[18], oo[19]);
        Orow[5] = make_float4(oo[20], oo[21], oo[22], oo[23]);
        Orow[6] = make_float4(oo[24], oo[25], oo[26], oo[27]);
        Orow[7] = make_float4(oo[28], oo[29], oo[30], oo[31]);
    }
}

// ---------------- host ----------------

extern "C" void kernel_launch(void* const* d_in, const int* in_sizes, int n_in,
                              void* d_out, int out_size, void* d_ws, size_t ws_size,
                              hipStream_t stream) {
    const float* h_from   = (const float*)d_in[0];
    const float* h_to_x   = (const float*)d_in[1];
    const float* h_to_z   = (const float*)d_in[2];
    const float* hx_logit = (const float*)d_in[3];
    const float* hz_logit = (const float*)d_in[4];
    const int*   from_x   = (const int*)d_in[5];
    const int*   to_x     = (const int*)d_in[6];
    const int*   from_z   = (const int*)d_in[7];
    const int*   to_z     = (const int*)d_in[8];
    const float* Wm1_x    = (const float*)d_in[9];
    const float* Wm2_x    = (const float*)d_in[10];
    const float* Wm1_z    = (const float*)d_in[11];
    const float* Wm2_z    = (const float*)d_in[12];
    const float* We1_x    = (const float*)d_in[13];
    const float* We2_x    = (const float*)d_in[14];
    const float* We1_z    = (const float*)d_in[15];
    const float* We2_z    = (const float*)d_in[16];

    // Workspace layout (bytes), end = 85,196,812 (within proven 85.3 MB budget)
    char* ws = (char*)d_ws;
    float* U2 = (float*)(ws);                                  // [NVN][NB][40] 41,943,040
    float* T2 = (float*)(ws + 41943040);                       // [NCN][NB][40] 20,971,520
    float* P2 = (float*)(ws + 62914560);                       // [NCN][NB][40] 20,971,520
    unsigned short* ef_x = (unsigned short*)(ws + 83886080);   // 524,288
    unsigned short* ef_z = (unsigned short*)(ws + 84410368);   // 524,288
    int* start_x = (int*)(ws + 84934656);                      // 131,076
    int* start_z = (int*)(ws + 85065736);                      // 131,076
    // counts/cursors alias U2's head: dead before precompU writes U2 (stream order)
    int* cnt_x = (int*)(ws + 0);
    int* cnt_z = (int*)(ws + 131072);
    float* out = (float*)d_out;

    hipMemsetAsync(ws, 0, 262144, stream);  // zero cnt_x + cnt_z
    hist_both<<<2048, 256, 0, stream>>>(to_x, to_z, cnt_x, cnt_z);
    scan_both<<<2, 1024, 0, stream>>>(cnt_x, cnt_z, start_x, start_z);
    scatter_both<<<2048, 256, 0, stream>>>(to_x, from_x, to_z, from_z,
                                           cnt_x, cnt_z, ef_x, ef_z);

    for (int side = 0; side < 2; side++) {
        const float* h_to   = side ? h_to_z   : h_to_x;
        const float* logit  = side ? hz_logit : hx_logit;
        const float* Wm1    = side ? Wm1_z    : Wm1_x;
        const float* Wm2    = side ? Wm2_z    : Wm2_x;
        const float* We1    = side ? We1_z    : We1_x;
        const float* We2    = side ? We2_z    : We2_x;
        const int*   startp = side ? start_z  : start_x;
        const unsigned short* efp = side ? ef_z : ef_x;
        float* out_s = out + (size_t)side * NB * NCN * DIM;

        precompU_kernel<<<NVN * NB / 256, 256, 0, stream>>>(h_from, Wm1, U2);
        precompTP_kernel<<<NCN * 8 / 256, 256, 0, stream>>>(h_to, logit, Wm1, We1, T2, P2);
        agg_kernel<<<NCN * 8 / 256, 256, 0, stream>>>(U2, T2, P2, startp, efp,
                                                      Wm2, We1, We2, out_s);
    }
}

// Round 5
// 386.637 us; speedup vs baseline: 1.2177x; 1.2177x over previous
//
#include <hip/hip_runtime.h>

// Problem constants (from reference)
#define NVN 65536
#define NCN 32768
#define NB 4
#define DIM 32
#define NE 262144
#define HID 40
#define MSGD 20

#define WE2_STRIDE 36  // padded row stride for we2s (breaks h-row bank aliasing)

__device__ __forceinline__ void fma4(float4& acc, float a, const float4 w) {
    acc.x += a * w.x; acc.y += a * w.y; acc.z += a * w.z; acc.w += a * w.w;
}
__device__ __forceinline__ void relu_acc4(float4& s, const float4 u, const float4 t) {
    s.x += fmaxf(u.x + t.x, 0.f); s.y += fmaxf(u.y + t.y, 0.f);
    s.z += fmaxf(u.z + t.z, 0.f); s.w += fmaxf(u.w + t.w, 0.f);
}

// ---------------- CSR build (both sides fused) ----------------

__global__ __launch_bounds__(256) void hist_both(const int* __restrict__ to_x,
                                                 const int* __restrict__ to_z,
                                                 int* __restrict__ cnt_x,
                                                 int* __restrict__ cnt_z) {
    int bid = blockIdx.x;
    int e = (bid & 1023) * 256 + threadIdx.x;
    if (bid < 1024) atomicAdd(&cnt_x[to_x[e]], 1);
    else            atomicAdd(&cnt_z[to_z[e]], 1);
}

__global__ __launch_bounds__(1024) void scan_both(int* __restrict__ cnt_x,
                                                  int* __restrict__ cnt_z,
                                                  int* __restrict__ start_x,
                                                  int* __restrict__ start_z) {
    int side = blockIdx.x;
    int* counts = side ? cnt_z : cnt_x;   // re-written in place as scatter cursor
    int* start  = side ? start_z : start_x;
    __shared__ int sd[1024];
    int t = threadIdx.x;
    int base = t * 32;
    int local[32];
    int s = 0;
#pragma unroll
    for (int i = 0; i < 32; i++) { local[i] = counts[base + i]; s += local[i]; }
    sd[t] = s;
    __syncthreads();
    for (int off = 1; off < 1024; off <<= 1) {
        int v = (t >= off) ? sd[t - off] : 0;
        __syncthreads();
        sd[t] += v;
        __syncthreads();
    }
    int run = sd[t] - s;
#pragma unroll
    for (int i = 0; i < 32; i++) {
        start[base + i] = run;
        counts[base + i] = run;   // cursor init
        run += local[i];
    }
    if (t == 1023) start[NCN] = run;
}

__global__ __launch_bounds__(256) void scatter_both(const int* __restrict__ to_x,
                                                    const int* __restrict__ from_x,
                                                    const int* __restrict__ to_z,
                                                    const int* __restrict__ from_z,
                                                    int* __restrict__ cnt_x,
                                                    int* __restrict__ cnt_z,
                                                    unsigned short* __restrict__ ef_x,
                                                    unsigned short* __restrict__ ef_z) {
    int bid = blockIdx.x;
    int e = (bid & 1023) * 256 + threadIdx.x;
    const int* t; const int* f; int* cur; unsigned short* ef;
    if (bid < 1024) { t = to_x; f = from_x; cur = cnt_x; ef = ef_x; }
    else            { t = to_z; f = from_z; cur = cnt_z; ef = ef_z; }
    int c = t[e];
    int pos = atomicAdd(&cur[c], 1);
    ef[pos] = (unsigned short)f[e];
}

// ------- Precompute U2[v][b][40] = h_from[b][v] @ Wm1[0:32] (quad per v, lane=b) -------

__global__ __launch_bounds__(256) void precompU_kernel(const float* __restrict__ h_from,
                                                       const float* __restrict__ Wm1,
                                                       float* __restrict__ U2) {
    __shared__ float w[DIM * HID];
    int tid = threadIdx.x;
    for (int i = tid; i < DIM * HID; i += 256) w[i] = Wm1[i];
    __syncthreads();
    int gt = blockIdx.x * 256 + tid;
    int v = gt >> 2;
    int b = gt & 3;
    const float4* hf4 = (const float4*)(h_from + ((size_t)b * NVN + v) * DIM);
    float acc[HID];
#pragma unroll
    for (int h = 0; h < HID; h++) acc[h] = 0.f;
#pragma unroll
    for (int q = 0; q < DIM / 4; q++) {
        float4 x = hf4[q];
#pragma unroll
        for (int h = 0; h < HID; h++) {
            acc[h] += x.x * w[(4 * q + 0) * HID + h];
            acc[h] += x.y * w[(4 * q + 1) * HID + h];
            acc[h] += x.z * w[(4 * q + 2) * HID + h];
            acc[h] += x.w * w[(4 * q + 3) * HID + h];
        }
    }
    float4* dst = (float4*)(U2 + ((size_t)v * NB + b) * HID);
#pragma unroll
    for (int q = 0; q < HID / 4; q++)
        dst[q] = make_float4(acc[4 * q], acc[4 * q + 1], acc[4 * q + 2], acc[4 * q + 3]);
}

// ------- Precompute T2[c][b][40], P2[c][b][40] (8 lanes per c: which x batch) -------

__global__ __launch_bounds__(256) void precompTP_kernel(const float* __restrict__ h_to,
                                                        const float* __restrict__ logit,
                                                        const float* __restrict__ Wm1,
                                                        const float* __restrict__ We1,
                                                        float* __restrict__ T2,
                                                        float* __restrict__ P2) {
    __shared__ float wm1b[DIM * HID];
    __shared__ float we1b[DIM * HID];
    __shared__ float we1l[HID];
    int tid = threadIdx.x;
    for (int i = tid; i < DIM * HID; i += 256) {
        wm1b[i] = Wm1[DIM * HID + i];   // rows 32..63
        we1b[i] = We1[MSGD * HID + i];  // rows 20..51
    }
    if (tid < HID) we1l[tid] = We1[(MSGD + DIM) * HID + tid];  // row 52
    __syncthreads();
    int gt = blockIdx.x * 256 + tid;
    int c = gt >> 3;
    int l8 = gt & 7;
    int b = l8 & 3;
    int which = l8 >> 2;   // 0: T, 1: P
    const float4* h4 = (const float4*)(h_to + ((size_t)b * NCN + c) * DIM);
    float lg = logit[(size_t)b * NCN + c];
    float lginit = which ? lg : 0.f;
    const float* wsel = which ? we1b : wm1b;
    float acc[HID];
#pragma unroll
    for (int h = 0; h < HID; h++) acc[h] = lginit * we1l[h];
#pragma unroll
    for (int q = 0; q < DIM / 4; q++) {
        float4 x = h4[q];
#pragma unroll
        for (int h = 0; h < HID; h++) {
            acc[h] += x.x * wsel[(4 * q + 0) * HID + h];
            acc[h] += x.y * wsel[(4 * q + 1) * HID + h];
            acc[h] += x.z * wsel[(4 * q + 2) * HID + h];
            acc[h] += x.w * wsel[(4 * q + 3) * HID + h];
        }
    }
    float* dstb = (which ? P2 : T2) + ((size_t)c * NB + b) * HID;
    float4* dst = (float4*)dstb;
#pragma unroll
    for (int q = 0; q < HID / 4; q++)
        dst[q] = make_float4(acc[4 * q], acc[4 * q + 1], acc[4 * q + 2], acc[4 * q + 3]);
}

// ------- Fused aggregate + embed MLP: EIGHT lanes per check node -------
// lane = (batch b, half): each lane owns 20 components; 8-lane group gathers one
// contiguous 640B U2 line per edge. m/o partials pair-reduced via shfl_xor(,4).
// NOTE: no min-waves clamp — VGPR must float to ~96-112 or the edge loop spills
// (round 3: cap 84 -> 127MB scratch writes; round 4: cap 64 -> 151MB. Round 2's
// unbounded 112-VGPR build had zero spill).

__global__ __launch_bounds__(256) void agg_kernel(const float* __restrict__ U2,
                                                  const float* __restrict__ T2,
                                                  const float* __restrict__ P2,
                                                  const int* __restrict__ start,
                                                  const unsigned short* __restrict__ ef,
                                                  const float* __restrict__ Wm2,
                                                  const float* __restrict__ We1,
                                                  const float* __restrict__ We2,
                                                  float* __restrict__ out) {
    __shared__ __attribute__((aligned(16))) float wm2s[HID * MSGD];        // [40][20]
    __shared__ __attribute__((aligned(16))) float we1s[MSGD * HID];        // [20][40]
    __shared__ __attribute__((aligned(16))) float we2s[HID * WE2_STRIDE];  // [40][36]
    int tid = threadIdx.x;
    for (int i = tid; i < HID * MSGD; i += 256) { wm2s[i] = Wm2[i]; we1s[i] = We1[i]; }
    for (int i = tid; i < HID * DIM; i += 256) {
        int h = i >> 5, d = i & 31;
        we2s[h * WE2_STRIDE + d] = We2[i];
    }
    __syncthreads();

    int gt = blockIdx.x * 256 + tid;
    int c = gt >> 3;
    int l8 = gt & 7;
    int b = l8 & 3;
    int half = l8 >> 2;
    int hoff = half * 20;   // this lane's component offset within the 40

    // T slice (20 floats)
    const float4* Tp = (const float4*)(T2 + ((size_t)c * NB + b) * HID + hoff);
    float4 t0 = Tp[0], t1 = Tp[1], t2 = Tp[2], t3 = Tp[3], t4 = Tp[4];

    float4 s0, s1, s2, s3, s4;
    s0 = s1 = s2 = s3 = s4 = make_float4(0.f, 0.f, 0.f, 0.f);

    int e0 = start[c], e1 = start[c + 1];
    const float* Ubase = U2 + b * HID + hoff;
    int vcur = (e0 < e1) ? (int)ef[e0] : 0;
    for (int i = e0; i < e1; ++i) {
        int vnext = (i + 1 < e1) ? (int)ef[i + 1] : 0;
        const float4* Up = (const float4*)(Ubase + (size_t)vcur * (NB * HID));
        float4 u0 = Up[0], u1 = Up[1], u2 = Up[2], u3 = Up[3], u4 = Up[4];
        relu_acc4(s0, u0, t0); relu_acc4(s1, u1, t1); relu_acc4(s2, u2, t2);
        relu_acc4(s3, u3, t3); relu_acc4(s4, u4, t4);
        vcur = vnext;
    }

    // ---- m partial: this lane's 20 h-rows of Wm2 ----
    float4 m4[5];
#pragma unroll
    for (int kq = 0; kq < 5; kq++) m4[kq] = make_float4(0.f, 0.f, 0.f, 0.f);
    const float* wmbase = wm2s + hoff * MSGD;
#define MROW(sv, k) { const float4* w4_ = (const float4*)(wmbase + (k) * MSGD); \
    fma4(m4[0], (sv), w4_[0]); fma4(m4[1], (sv), w4_[1]); fma4(m4[2], (sv), w4_[2]); \
    fma4(m4[3], (sv), w4_[3]); fma4(m4[4], (sv), w4_[4]); }
    MROW(s0.x, 0)  MROW(s0.y, 1)  MROW(s0.z, 2)  MROW(s0.w, 3)
    MROW(s1.x, 4)  MROW(s1.y, 5)  MROW(s1.z, 6)  MROW(s1.w, 7)
    MROW(s2.x, 8)  MROW(s2.y, 9)  MROW(s2.z, 10) MROW(s2.w, 11)
    MROW(s3.x, 12) MROW(s3.y, 13) MROW(s3.z, 14) MROW(s3.w, 15)
    MROW(s4.x, 16) MROW(s4.y, 17) MROW(s4.z, 18) MROW(s4.w, 19)
#undef MROW

    float mm[MSGD];
#pragma unroll
    for (int kq = 0; kq < 5; kq++) {
        mm[4 * kq + 0] = m4[kq].x; mm[4 * kq + 1] = m4[kq].y;
        mm[4 * kq + 2] = m4[kq].z; mm[4 * kq + 3] = m4[kq].w;
    }
    // pair-reduce across the two halves (lane ^ 4) -> full m in every lane
#pragma unroll
    for (int k = 0; k < MSGD; k++) mm[k] += __shfl_xor(mm[k], 4);

    // ---- a = relu(m @ We1[0:20] + P) for this lane's 20 components ----
    const float4* Pp = (const float4*)(P2 + ((size_t)c * NB + b) * HID + hoff);
    float4 a0 = Pp[0], a1 = Pp[1], a2 = Pp[2], a3 = Pp[3], a4 = Pp[4];
#pragma unroll
    for (int k = 0; k < MSGD; k++) {
        float mk = mm[k];
        const float4* w4 = (const float4*)(we1s + k * HID + hoff);
        fma4(a0, mk, w4[0]); fma4(a1, mk, w4[1]); fma4(a2, mk, w4[2]);
        fma4(a3, mk, w4[3]); fma4(a4, mk, w4[4]);
    }
    a0.x = fmaxf(a0.x, 0.f); a0.y = fmaxf(a0.y, 0.f); a0.z = fmaxf(a0.z, 0.f); a0.w = fmaxf(a0.w, 0.f);
    a1.x = fmaxf(a1.x, 0.f); a1.y = fmaxf(a1.y, 0.f); a1.z = fmaxf(a1.z, 0.f); a1.w = fmaxf(a1.w, 0.f);
    a2.x = fmaxf(a2.x, 0.f); a2.y = fmaxf(a2.y, 0.f); a2.z = fmaxf(a2.z, 0.f); a2.w = fmaxf(a2.w, 0.f);
    a3.x = fmaxf(a3.x, 0.f); a3.y = fmaxf(a3.y, 0.f); a3.z = fmaxf(a3.z, 0.f); a3.w = fmaxf(a3.w, 0.f);
    a4.x = fmaxf(a4.x, 0.f); a4.y = fmaxf(a4.y, 0.f); a4.z = fmaxf(a4.z, 0.f); a4.w = fmaxf(a4.w, 0.f);

    // ---- o partial: this lane's 20 h-rows of We2 ----
    float4 o4[8];
#pragma unroll
    for (int dq = 0; dq < 8; dq++) o4[dq] = make_float4(0.f, 0.f, 0.f, 0.f);
    const float* wobase = we2s + hoff * WE2_STRIDE;
#define OROW(av, k) { const float4* w4_ = (const float4*)(wobase + (k) * WE2_STRIDE); \
    fma4(o4[0], (av), w4_[0]); fma4(o4[1], (av), w4_[1]); fma4(o4[2], (av), w4_[2]); \
    fma4(o4[3], (av), w4_[3]); fma4(o4[4], (av), w4_[4]); fma4(o4[5], (av), w4_[5]); \
    fma4(o4[6], (av), w4_[6]); fma4(o4[7], (av), w4_[7]); }
    OROW(a0.x, 0)  OROW(a0.y, 1)  OROW(a0.z, 2)  OROW(a0.w, 3)
    OROW(a1.x, 4)  OROW(a1.y, 5)  OROW(a1.z, 6)  OROW(a1.w, 7)
    OROW(a2.x, 8)  OROW(a2.y, 9)  OROW(a2.z, 10) OROW(a2.w, 11)
    OROW(a3.x, 12) OROW(a3.y, 13) OROW(a3.z, 14) OROW(a3.w, 15)
    OROW(a4.x, 16) OROW(a4.y, 17) OROW(a4.z, 18) OROW(a4.w, 19)
#undef OROW

    float oo[DIM];
#pragma unroll
    for (int dq = 0; dq < 8; dq++) {
        oo[4 * dq + 0] = o4[dq].x; oo[4 * dq + 1] = o4[dq].y;
        oo[4 * dq + 2] = o4[dq].z; oo[4 * dq + 3] = o4[dq].w;
    }
#pragma unroll
    for (int d = 0; d < DIM; d++) oo[d] += __shfl_xor(oo[d], 4);

    float4* Orow = (float4*)(out + ((size_t)b * NCN + c) * DIM);
    if (half == 0) {
        Orow[0] = make_float4(oo[0], oo[1], oo[2], oo[3]);
        Orow[1] = make_float4(oo[4], oo[5], oo[6], oo[7]);
        Orow[2] = make_float4(oo[8], oo[9], oo[10], oo[11]);
        Orow[3] = make_float4(oo[12], oo[13], oo[14], oo[15]);
    } else {
        Orow[4] = make_float4(oo[16], oo[17], oo[18], oo[19]);
        Orow[5] = make_float4(oo[20], oo[21], oo[22], oo[23]);
        Orow[6] = make_float4(oo[24], oo[25], oo[26], oo[27]);
        Orow[7] = make_float4(oo[28], oo[29], oo[30], oo[31]);
    }
}

// ---------------- host ----------------

extern "C" void kernel_launch(void* const* d_in, const int* in_sizes, int n_in,
                              void* d_out, int out_size, void* d_ws, size_t ws_size,
                              hipStream_t stream) {
    const float* h_from   = (const float*)d_in[0];
    const float* h_to_x   = (const float*)d_in[1];
    const float* h_to_z   = (const float*)d_in[2];
    const float* hx_logit = (const float*)d_in[3];
    const float* hz_logit = (const float*)d_in[4];
    const int*   from_x   = (const int*)d_in[5];
    const int*   to_x     = (const int*)d_in[6];
    const int*   from_z   = (const int*)d_in[7];
    const int*   to_z     = (const int*)d_in[8];
    const float* Wm1_x    = (const float*)d_in[9];
    const float* Wm2_x    = (const float*)d_in[10];
    const float* Wm1_z    = (const float*)d_in[11];
    const float* Wm2_z    = (const float*)d_in[12];
    const float* We1_x    = (const float*)d_in[13];
    const float* We2_x    = (const float*)d_in[14];
    const float* We1_z    = (const float*)d_in[15];
    const float* We2_z    = (const float*)d_in[16];

    // Workspace layout (bytes), end = 85,196,812 (within proven 85.3 MB budget)
    char* ws = (char*)d_ws;
    float* U2 = (float*)(ws);                                  // [NVN][NB][40] 41,943,040
    float* T2 = (float*)(ws + 41943040);                       // [NCN][NB][40] 20,971,520
    float* P2 = (float*)(ws + 62914560);                       // [NCN][NB][40] 20,971,520
    unsigned short* ef_x = (unsigned short*)(ws + 83886080);   // 524,288
    unsigned short* ef_z = (unsigned short*)(ws + 84410368);   // 524,288
    int* start_x = (int*)(ws + 84934656);                      // 131,076
    int* start_z = (int*)(ws + 85065736);                      // 131,076
    // counts/cursors alias U2's head: dead before precompU writes U2 (stream order)
    int* cnt_x = (int*)(ws + 0);
    int* cnt_z = (int*)(ws + 131072);
    float* out = (float*)d_out;

    hipMemsetAsync(ws, 0, 262144, stream);  // zero cnt_x + cnt_z
    hist_both<<<2048, 256, 0, stream>>>(to_x, to_z, cnt_x, cnt_z);
    scan_both<<<2, 1024, 0, stream>>>(cnt_x, cnt_z, start_x, start_z);
    scatter_both<<<2048, 256, 0, stream>>>(to_x, from_x, to_z, from_z,
                                           cnt_x, cnt_z, ef_x, ef_z);

    for (int side = 0; side < 2; side++) {
        const float* h_to   = side ? h_to_z   : h_to_x;
        const float* logit  = side ? hz_logit : hx_logit;
        const float* Wm1    = side ? Wm1_z    : Wm1_x;
        const float* Wm2    = side ? Wm2_z    : Wm2_x;
        const float* We1    = side ? We1_z    : We1_x;
        const float* We2    = side ? We2_z    : We2_x;
        const int*   startp = side ? start_z  : start_x;
        const unsigned short* efp = side ? ef_z : ef_x;
        float* out_s = out + (size_t)side * NB * NCN * DIM;

        precompU_kernel<<<NVN * NB / 256, 256, 0, stream>>>(h_from, Wm1, U2);
        precompTP_kernel<<<NCN * 8 / 256, 256, 0, stream>>>(h_to, logit, Wm1, We1, T2, P2);
        agg_kernel<<<NCN * 8 / 256, 256, 0, stream>>>(U2, T2, P2, startp, efp,
                                                      Wm2, We1, We2, out_s);
    }
}